// Round 14
// baseline (290.678 us; speedup 1.0000x reference)
//
#include <hip/hip_runtime.h>
#include <hip/hip_bf16.h>

// ---------------- problem constants ----------------
#define T_SEQ 8192
#define DMODEL 1024
#define DINNER 2048          // DI
#define NSTATE 16            // DS
#define NCH 128              // scan chunks
#define CL 64                // chunk length (NCH*CL = T_SEQ)

typedef __attribute__((ext_vector_type(8))) short bf16x8;   // 8 bf16 = 4 VGPRs
typedef __attribute__((ext_vector_type(4))) float f32x4;    // MFMA C/D frag

__device__ __forceinline__ float bf2f(ushort u) {
  union { unsigned u; float f; } c; c.u = ((unsigned)u) << 16; return c.f;
}
__device__ __forceinline__ ushort f2bf(float f) {
  union { float f; unsigned u; } c; c.f = f;
  unsigned r = c.u + 0x7FFFu + ((c.u >> 16) & 1u);   // RNE
  return (ushort)(r >> 16);
}

#define GLD16(dst, src) __builtin_amdgcn_global_load_lds( \
    (const __attribute__((address_space(1))) void*)(src), \
    (__attribute__((address_space(3))) void*)(dst), 16, 0, 0)

template<int N> __device__ __forceinline__ void waitcnt_vm() {
  asm volatile("s_waitcnt vmcnt(%0)" :: "i"(N) : "memory");
}

// ---------------- fused prep kernel (cast + 2 transposes + wx pad) ----------------
__global__ __launch_bounds__(256) void prep_all(const float* __restrict__ x,
                                                const float* __restrict__ W_in,
                                                const float* __restrict__ W_out,
                                                const float* __restrict__ Wx,
                                                ushort* __restrict__ xbf,
                                                ushort* __restrict__ winT,
                                                ushort* __restrict__ woutT,
                                                ushort* __restrict__ wxT) {
  __shared__ float tile[32][33];
  int b = blockIdx.x, tid = threadIdx.x;
  if (b < 8192) {                       // cast: 8192*256 float4
    int i = b * 256 + tid;
    float4 v = ((const float4*)x)[i];
    ushort4 o;
    o.x = f2bf(v.x); o.y = f2bf(v.y); o.z = f2bf(v.z); o.w = f2bf(v.w);
    ((ushort4*)xbf)[i] = o;
    return;
  }
  b -= 8192;
  const float* in; ushort* out; int R, C, bx, by;
  if (b < 4096)      { in = W_in;  out = winT;  R = 1024; C = 4096; bx = b & 127; by = b >> 7; }
  else if (b < 6144) { b -= 4096; in = W_out; out = woutT; R = 2048; C = 1024; bx = b & 31; by = b >> 5; }
  else {                                // wx pad: 384 blocks
    int idx = (b - 6144) * 256 + tid;   // 48*2048
    int j = idx >> 11, k = idx & 2047;
    wxT[idx] = (j < 33) ? f2bf(Wx[k * 33 + j]) : (ushort)0;
    return;
  }
  int xx = tid & 31, yy = tid >> 5;     // 32 x 8
  bx *= 32; by *= 32;
#pragma unroll
  for (int j = 0; j < 32; j += 8)
    tile[yy + j][xx] = in[(size_t)(by + yy + j) * C + bx + xx];
  __syncthreads();
#pragma unroll
  for (int j = 0; j < 32; j += 8)
    out[(size_t)(bx + yy + j) * R + by + xx] = f2bf(tile[xx][yy + j]);
}

// ------------- minimal-fence GEMM: (MR*32)x256, BK=64, 2-buf -------------
// R13 post-mortem: 8 schedule variants all pinned at ~6800 cyc/K-tile because
// BAR()/LGKM0() embedded sched_barrier(0) x12/K-tile = m141 self-sabotage
// (order-pinning defeats compiler scheduling; m97's 2-barrier unpinned loop is
// the proven shape). This kernel: per K-tile exactly
//   reads(24 b128, C++ derefs - compiler dep-tracked)
//   lgkmcnt(0); s_barrier; sched_barrier(0)   <- read-publish (stage can't race)
//   stage tile t+2 (S x GLD16 into buf b, now free)
//   setprio(1); 64 MFMA; setprio(0)           <- compiler interleaves freely
//   vmcnt(S); s_barrier; sched_barrier(0)     <- t+1 landed, t+2 in flight
// Ledger: tile tau staged mid-tile tau-2; at t's end-vmcnt outstanding = t+2's S
// -> vmcnt(S) forces t+1 (issued a full tile back >> 900cy HBM). Tail: vmcnt(0).
// Swizzle: 16B slot s of 128B row r at s^(r&7); pre-swizzled global source
// (rule #21), same XOR on ds_read (0 conflicts measured R7-R13).
// 8 waves (2M x 4N), per-wave (MR*16)x64, acc[MR][4]. OUTMODE 0=f32, 1=bf16 split.
template<int OUTMODE, int MR>
__global__ __launch_bounds__(512, 2)
void gemm_min(const ushort* __restrict__ A, const ushort* __restrict__ B,
              void* __restrict__ out0, void* __restrict__ out1,
              int N, int K, int LDK, int MX) {
  constexpr int BM = MR * 32;
  constexpr int AHL = BM / 128;         // GLD16/thread per A-half
  constexpr int S = (BM + 256) / 64;    // stage GLD16/thread per K-tile
  extern __shared__ __align__(16) char smem[];
  char* const sBr = smem + 2 * BM * 128;

  const int tid = threadIdx.x, lane = tid & 63, wid = tid >> 6;
  const int wm = wid >> 2, wn = wid & 3;
  const int xcd = blockIdx.x & 7, jb = blockIdx.x >> 3;
  const int mtile = xcd * MX + (jb % MX), ntile = jb / MX;
  const int mbase = mtile * BM, nbase = ntile * 256;
  const int NT = K >> 6;

  const int sr = tid >> 3;
  const int scol = ((tid & 7) ^ (sr & 7)) << 3;
  const ushort* pA = A + (size_t)(mbase + sr) * LDK + scol;
  const ushort* pB = B + (size_t)(nbase + sr) * LDK + scol;

  auto stage = [&](int buf, int tt) {   // full K-tile: A (2 halves) + B (2 halves)
#pragma unroll
    for (int h = 0; h < 2; ++h)
#pragma unroll
      for (int r = 0; r < AHL; ++r)
        GLD16(smem + buf * (BM * 128) + (h * (BM / 2) + r * 64) * 128 + wid * 1024,
              pA + (size_t)(h * (BM / 2) + r * 64) * LDK + (size_t)tt * 64);
#pragma unroll
    for (int h = 0; h < 2; ++h)
#pragma unroll
      for (int r = 0; r < 2; ++r)
        GLD16(sBr + buf * 32768 + (h * 128 + r * 64) * 128 + wid * 1024,
              pB + (size_t)(h * 128 + r * 64) * LDK + (size_t)tt * 64);
  };

  const int frow = lane & 15, hh = lane >> 4;
  const int sw[2] = { ((hh) ^ (frow & 7)) << 4, ((4 + hh) ^ (frow & 7)) << 4 };
  const int arow = (wm * (MR * 16) + frow) * 128;
  const int brow = (wn * 64 + frow) * 128;

  f32x4 acc[MR][4];
#pragma unroll
  for (int m = 0; m < MR; ++m)
#pragma unroll
    for (int n = 0; n < 4; ++n) acc[m][n] = (f32x4){0.f, 0.f, 0.f, 0.f};

  // prologue: tiles 0,1 fully staged; force tile 0 landed (leave tile 1's S)
  stage(0, 0);
  if (NT > 1) stage(1, 1);
  waitcnt_vm<S>();
  __builtin_amdgcn_s_barrier();
  __builtin_amdgcn_sched_barrier(0);

  for (int t = 0; t < NT; ++t) {
    const int b = t & 1;
    const char* bA = smem + b * (BM * 128);
    const char* bB = sBr + b * 32768;

    // ---- reads: all fragments for this K-tile (compiler dep-tracked)
    bf16x8 af[MR][2], bv[4][2];
#pragma unroll
    for (int m = 0; m < MR; ++m)
#pragma unroll
      for (int kk = 0; kk < 2; ++kk)
        af[m][kk] = *(const bf16x8*)(bA + arow + m * 2048 + sw[kk]);
#pragma unroll
    for (int n = 0; n < 4; ++n)
#pragma unroll
      for (int kk = 0; kk < 2; ++kk)
        bv[n][kk] = *(const bf16x8*)(bB + brow + n * 2048 + sw[kk]);

    // ---- read-publish: all waves' reads of buf b complete before restaging it
    asm volatile("s_waitcnt lgkmcnt(0)" ::: "memory");
    __builtin_amdgcn_s_barrier();
    __builtin_amdgcn_sched_barrier(0);

    // ---- stage tile t+2 into buf b (now free)
    if (t + 2 < NT) stage(b, t + 2);

    // ---- compute (compiler interleaves with stage issue)
    __builtin_amdgcn_s_setprio(1);
#pragma unroll
    for (int kk = 0; kk < 2; ++kk)
#pragma unroll
      for (int m = 0; m < MR; ++m)
#pragma unroll
        for (int n = 0; n < 4; ++n)
          acc[m][n] = __builtin_amdgcn_mfma_f32_16x16x32_bf16(af[m][kk], bv[n][kk], acc[m][n], 0, 0, 0);
    __builtin_amdgcn_s_setprio(0);

    // ---- counted vmcnt: force t+1 landed, keep t+2 in flight
    if (t + 2 < NT) waitcnt_vm<S>(); else waitcnt_vm<0>();
    __builtin_amdgcn_s_barrier();
    __builtin_amdgcn_sched_barrier(0);
  }

  // epilogue: C/D layout col=lane&15, row=(lane>>4)*4+reg  [m89/m91]
  const int crow0 = mbase + wm * (MR * 16) + (lane >> 4) * 4;
  const int ccol0 = wn * 64 + (lane & 15);
  if (OUTMODE == 0) {
    float* po = (float*)out0;
#pragma unroll
    for (int m = 0; m < MR; ++m)
#pragma unroll
      for (int n = 0; n < 4; ++n)
#pragma unroll
        for (int j = 0; j < 4; ++j)
          po[(size_t)(crow0 + m * 16 + j) * N + nbase + ccol0 + n * 16] = acc[m][n][j];
  } else {
    ushort* dst = (nbase < 2048) ? (ushort*)out0 : (ushort*)out1;
    const int cbase = (nbase & 2047) + ccol0;
#pragma unroll
    for (int m = 0; m < MR; ++m)
#pragma unroll
      for (int n = 0; n < 4; ++n)
#pragma unroll
        for (int j = 0; j < 4; ++j)
          dst[(size_t)(crow0 + m * 16 + j) * 2048 + cbase + n * 16] = f2bf(acc[m][n][j]);
  }
}

// ---------------- thin GEMM: parts[j] = xs @ W_x (N=48 pad), 4-way split-K ----------------
__global__ __launch_bounds__(256) void gemm_thin(const ushort* __restrict__ A,
                                                 const ushort* __restrict__ Bw,
                                                 float* __restrict__ part) {
  __shared__ __align__(16) ushort sA[128 * 64];
  __shared__ __align__(16) ushort sB[48 * 64];
  const int tid = threadIdx.x, lane = tid & 63, wid = tid >> 6;
  const int mbase = blockIdx.x * 128;
  const int kbase = blockIdx.y * 512;
  const int frow = lane & 15, fke = (lane >> 4) * 8;

  f32x4 acc[2][3];
#pragma unroll
  for (int m = 0; m < 2; ++m)
#pragma unroll
    for (int n = 0; n < 3; ++n) acc[m][n] = (f32x4){0.f, 0.f, 0.f, 0.f};

  for (int k0 = 0; k0 < 512; k0 += 64) {
#pragma unroll
    for (int j = 0; j < 4; ++j) {
      int o = tid * 16 + j * 4096;
      int row = o >> 7, ke = ((o >> 4) & 7) * 8;
      GLD16((char*)sA + wid * 1024 + j * 4096,
            A + (size_t)(mbase + row) * DINNER + kbase + k0 + ke);
    }
    for (int i = tid; i < 384; i += 256) {
      int brow = i >> 3, kc = (i & 7) * 8;
      *(bf16x8*)&sB[brow * 64 + kc] = *(const bf16x8*)(Bw + (size_t)brow * DINNER + kbase + k0 + kc);
    }
    __syncthreads();
    bf16x8 af[2][2], bf_[3][2];
#pragma unroll
    for (int m = 0; m < 2; ++m)
#pragma unroll
      for (int ks = 0; ks < 2; ++ks)
        af[m][ks] = *(const bf16x8*)&sA[(wid * 32 + m * 16 + frow) * 64 + ks * 32 + fke];
#pragma unroll
    for (int n = 0; n < 3; ++n)
#pragma unroll
      for (int ks = 0; ks < 2; ++ks)
        bf_[n][ks] = *(const bf16x8*)&sB[(n * 16 + frow) * 64 + ks * 32 + fke];
#pragma unroll
    for (int ks = 0; ks < 2; ++ks)
#pragma unroll
      for (int m = 0; m < 2; ++m)
#pragma unroll
        for (int n = 0; n < 3; ++n)
          acc[m][n] = __builtin_amdgcn_mfma_f32_16x16x32_bf16(af[m][ks], bf_[n][ks], acc[m][n], 0, 0, 0);
    __syncthreads();
  }
  float* po = part + (size_t)blockIdx.y * (T_SEQ * 48);
#pragma unroll
  for (int m = 0; m < 2; ++m)
#pragma unroll
    for (int n = 0; n < 3; ++n)
#pragma unroll
      for (int j = 0; j < 4; ++j) {
        int rr = mbase + wid * 32 + m * 16 + (lane >> 4) * 4 + j;
        int cc = n * 16 + (lane & 15);
        po[(size_t)rr * 48 + cc] = acc[m][n][j];
      }
}

// -------- depthwise causal conv (DC=4) + silu, scalar (coalesced weights) --------
__global__ __launch_bounds__(256) void conv_silu(const ushort* __restrict__ xc,
                                                 const float* __restrict__ cw,
                                                 const float* __restrict__ cb,
                                                 ushort* __restrict__ xs) {
  int idx = blockIdx.x * 256 + threadIdx.x;
  int t = idx >> 11, d = idx & 2047;
  float4 w = *(const float4*)(cw + d * 4);
  float a = cb[d];
  const float wk[4] = {w.x, w.y, w.z, w.w};
#pragma unroll
  for (int k = 0; k < 4; ++k) {
    int tt = t - 3 + k;
    if (tt >= 0) a += bf2f(xc[(size_t)tt * 2048 + d]) * wk[k];
  }
  float s = a / (1.f + expf(-a));
  xs[idx] = f2bf(s);
}

// ---- fused: split-K reduce + delta/abar/bbar/cc + chunk products P ----
__global__ __launch_bounds__(256) void precompute_k(const float* __restrict__ part,
                                                    const float* __restrict__ A_log,
                                                    float* __restrict__ abar,
                                                    float* __restrict__ bbar,
                                                    float* __restrict__ cc,
                                                    float* __restrict__ P) {
  __shared__ float ld[256 * 33];
  const int t0 = blockIdx.x * 256, tid = threadIdx.x;
  for (int i = tid; i < 256 * 33; i += 256) {
    int r = i / 33, col = i - r * 33;
    size_t off = (size_t)(t0 + r) * 48 + col;
    ld[i] = part[off] + part[(size_t)T_SEQ * 48 + off] +
            part[2 * (size_t)T_SEQ * 48 + off] + part[3 * (size_t)T_SEQ * 48 + off];
  }
  __syncthreads();
  const float* r = &ld[tid * 33];
  float v = r[0];
  float delta = (v > 20.f) ? v : log1pf(expf(v));
  int t = t0 + tid;
#pragma unroll
  for (int n = 0; n < NSTATE; ++n) {
    float A = -expf(A_log[n]);
    abar[t * 16 + n] = expf(delta * A);
    bbar[t * 16 + n] = delta * r[1 + n];
    cc[t * 16 + n]   = r[17 + n];
  }
  float s = delta;
#pragma unroll
  for (int off = 32; off > 0; off >>= 1) s += __shfl_down(s, off);
  s = __shfl(s, 0);
  int lane = tid & 63, c = blockIdx.x * 4 + (tid >> 6);
  if (lane < 16) P[c * 16 + lane] = expf(-expf(A_log[lane]) * s);
}

// ---------------- scan pass 1 (hend bf16) ----------------
__global__ __launch_bounds__(256) void scan1(const ushort* __restrict__ xs,
                                             const float* __restrict__ abar,
                                             const float* __restrict__ bbar,
                                             ushort* __restrict__ hend) {
  int c = blockIdx.x;
  int d = blockIdx.y * 256 + threadIdx.x;
  __shared__ float s_ab[CL * 16], s_bb[CL * 16];
  for (int e = threadIdx.x; e < CL * 16; e += 256) {
    s_ab[e] = abar[(size_t)c * CL * 16 + e];
    s_bb[e] = bbar[(size_t)c * CL * 16 + e];
  }
  __syncthreads();
  float h[16];
#pragma unroll
  for (int n = 0; n < 16; ++n) h[n] = 0.f;
  int tbase = c * CL;
  for (int i = 0; i < CL; ++i) {
    float x = bf2f(xs[(size_t)(tbase + i) * DINNER + d]);
#pragma unroll
    for (int n = 0; n < 16; ++n) h[n] = s_ab[i * 16 + n] * h[n] + s_bb[i * 16 + n] * x;
  }
  ushort* o = hend + ((size_t)c * DINNER + d) * 16;
  bf16x8 o0, o1;
#pragma unroll
  for (int q = 0; q < 8; ++q) { o0[q] = (short)f2bf(h[q]); o1[q] = (short)f2bf(h[8 + q]); }
  *(bf16x8*)o = o0;
  *(bf16x8*)(o + 8) = o1;
}

// ---------------- scan pass 2: blocked-prefetch carry scan ----------------
__global__ __launch_bounds__(128) void scan2(const ushort* __restrict__ hend,
                                             const float* __restrict__ P,
                                             ushort* __restrict__ hin) {
  int idx = blockIdx.x * 128 + threadIdx.x;
  int n = idx & 15;
  float h = 0.f;
  for (int g = 0; g < 16; ++g) {
    float e[8], p[8];
#pragma unroll
    for (int j = 0; j < 8; ++j) {
      e[j] = bf2f(hend[(size_t)(g * 8 + j) * 32768 + idx]);
      p[j] = P[(g * 8 + j) * 16 + n];
    }
#pragma unroll
    for (int j = 0; j < 8; ++j) {
      hin[(size_t)(g * 8 + j) * 32768 + idx] = f2bf(h);
      h = p[j] * h + e[j];
    }
  }
}

// ---------------- scan pass 3 (hin bf16) ----------------
__global__ __launch_bounds__(256) void scan3(const ushort* __restrict__ xs,
                                             const ushort* __restrict__ zb,
                                             const float* __restrict__ abar,
                                             const float* __restrict__ bbar,
                                             const float* __restrict__ cc,
                                             const ushort* __restrict__ hin,
                                             const float* __restrict__ Dv,
                                             ushort* __restrict__ y) {
  int c = blockIdx.x;
  int d = blockIdx.y * 256 + threadIdx.x;
  __shared__ float s_ab[CL * 16], s_bb[CL * 16], s_cc[CL * 16];
  for (int e = threadIdx.x; e < CL * 16; e += 256) {
    s_ab[e] = abar[(size_t)c * CL * 16 + e];
    s_bb[e] = bbar[(size_t)c * CL * 16 + e];
    s_cc[e] = cc[(size_t)c * CL * 16 + e];
  }
  __syncthreads();
  float h[16];
  const ushort* hi = hin + ((size_t)c * DINNER + d) * 16;
  bf16x8 h0 = *(const bf16x8*)hi, h1 = *(const bf16x8*)(hi + 8);
#pragma unroll
  for (int q = 0; q < 8; ++q) { h[q] = bf2f((ushort)h0[q]); h[8 + q] = bf2f((ushort)h1[q]); }
  float Dd = Dv[d];
  int tbase = c * CL;
  for (int i = 0; i < CL; ++i) {
    size_t t = tbase + i;
    float x = bf2f(xs[t * DINNER + d]);
    float ys = 0.f;
#pragma unroll
    for (int n = 0; n < 16; ++n) {
      h[n] = s_ab[i * 16 + n] * h[n] + s_bb[i * 16 + n] * x;
      ys += s_cc[i * 16 + n] * h[n];
    }
    float z = bf2f(zb[t * 2048 + d]);
    float yv = (ys + Dd * x) * (z / (1.f + expf(-z)));
    y[t * DINNER + d] = f2bf(yv);
  }
}

// ---------------- launch ----------------
extern "C" void kernel_launch(void* const* d_in, const int* in_sizes, int n_in,
                              void* d_out, int out_size, void* d_ws, size_t ws_size,
                              hipStream_t stream) {
  const float* x      = (const float*)d_in[0];
  const float* W_in   = (const float*)d_in[1];
  const float* conv_w = (const float*)d_in[2];
  const float* conv_b = (const float*)d_in[3];
  const float* W_x    = (const float*)d_in[4];
  const float* A_log  = (const float*)d_in[5];
  const float* Dv     = (const float*)d_in[6];
  const float* W_out  = (const float*)d_in[7];
  float* out = (float*)d_out;

  char* w = (char*)d_ws;
  auto alloc = [&](size_t bytes) { char* p = w; w += (bytes + 255) & ~(size_t)255; return p; };

  ushort* xbf   = (ushort*)alloc((size_t)T_SEQ * DMODEL * 2);
  ushort* winT  = (ushort*)alloc((size_t)4096 * 1024 * 2);
  ushort* woutT = (ushort*)alloc((size_t)1024 * 2048 * 2);
  ushort* wxT   = (ushort*)alloc((size_t)48 * 2048 * 2);
  ushort* xc    = (ushort*)alloc((size_t)T_SEQ * DINNER * 2);
  ushort* zb    = (ushort*)alloc((size_t)T_SEQ * DINNER * 2);
  ushort* xs    = (ushort*)alloc((size_t)T_SEQ * DINNER * 2);
  float*  parts = (float*) alloc((size_t)4 * T_SEQ * 48 * 4);
  float*  abar  = (float*) alloc((size_t)T_SEQ * 16 * 4);
  float*  bbar  = (float*) alloc((size_t)T_SEQ * 16 * 4);
  float*  ccb   = (float*) alloc((size_t)T_SEQ * 16 * 4);
  float*  P     = (float*) alloc((size_t)NCH * 16 * 4);
  ushort* hend  = (ushort*)alloc((size_t)NCH * DINNER * 16 * 2);
  ushort* hin   = (ushort*)alloc((size_t)NCH * DINNER * 16 * 2);
  ushort* ybf   = (ushort*)alloc((size_t)T_SEQ * DINNER * 2);

  auto kg1 = gemm_min<1, 8>;   // 256x256, bf16 split out
  auto kg3 = gemm_min<0, 4>;   // 128x256, f32 out
  hipFuncSetAttribute(reinterpret_cast<const void*>(kg1),
                      hipFuncAttributeMaxDynamicSharedMemorySize, 131072);
  hipFuncSetAttribute(reinterpret_cast<const void*>(kg3),
                      hipFuncAttributeMaxDynamicSharedMemorySize, 98304);

  // fused prep: cast + W_in^T + W_out^T + wx pad
  prep_all<<<dim3(14720), 256, 0, stream>>>(x, W_in, W_out, W_x, xbf, winT, woutT, wxT);

  // GEMM1: [xc|z] = x @ W_in (8192x4096, K=1024); 512 blocks, MX=4
  kg1<<<dim3(512), 512, 131072, stream>>>(xbf, winT, xc, zb, 4096, 1024, 1024, 4);

  // conv + silu
  conv_silu<<<(T_SEQ * DINNER) / 256, 256, 0, stream>>>(xc, conv_w, conv_b, xs);

  // GEMM2: parts = xs @ W_x (N=48 pad, split-K 4)
  gemm_thin<<<dim3(T_SEQ / 128, 4), 256, 0, stream>>>(xs, wxT, parts);

  // fused reduce + precompute + chunk products
  precompute_k<<<32, 256, 0, stream>>>(parts, A_log, abar, bbar, ccb, P);

  // 3-pass chunked scan (bf16 carries)
  scan1<<<dim3(NCH, DINNER / 256), 256, 0, stream>>>(xs, abar, bbar, hend);
  scan2<<<256, 128, 0, stream>>>(hend, P, hin);
  scan3<<<dim3(NCH, DINNER / 256), 256, 0, stream>>>(xs, zb, abar, bbar, ccb, hin, Dv, ybf);

  // GEMM3: out = y @ W_out (8192x1024, K=2048); 256 blocks, MX=8
  kg3<<<dim3(256), 512, 98304, stream>>>(ybf, woutT, out, nullptr, 1024, 2048, 2048, 8);
}

// Round 15
// 283.944 us; speedup vs baseline: 1.0237x; 1.0237x over previous
//
#include <hip/hip_runtime.h>
#include <hip/hip_bf16.h>

// ---------------- problem constants ----------------
#define T_SEQ 8192
#define DMODEL 1024
#define DINNER 2048          // DI
#define NSTATE 16            // DS
#define NCH 128              // scan chunks
#define CL 64                // chunk length (NCH*CL = T_SEQ)

typedef __attribute__((ext_vector_type(8))) short bf16x8;   // 8 bf16 = 4 VGPRs
typedef __attribute__((ext_vector_type(4))) float f32x4;    // MFMA C/D frag

__device__ __forceinline__ float bf2f(ushort u) {
  union { unsigned u; float f; } c; c.u = ((unsigned)u) << 16; return c.f;
}
__device__ __forceinline__ ushort f2bf(float f) {
  union { float f; unsigned u; } c; c.f = f;
  unsigned r = c.u + 0x7FFFu + ((c.u >> 16) & 1u);   // RNE
  return (ushort)(r >> 16);
}

#define GLD16(dst, src) __builtin_amdgcn_global_load_lds( \
    (const __attribute__((address_space(1))) void*)(src), \
    (__attribute__((address_space(3))) void*)(dst), 16, 0, 0)

template<int N> __device__ __forceinline__ void waitcnt_vm() {
  asm volatile("s_waitcnt vmcnt(%0)" :: "i"(N) : "memory");
}
#define LGKM0() do { asm volatile("s_waitcnt lgkmcnt(0)" ::: "memory"); \
                     __builtin_amdgcn_sched_barrier(0); } while (0)
#define BAR() do { __builtin_amdgcn_s_barrier(); \
                   __builtin_amdgcn_sched_barrier(0); } while (0)

// ---------------- fused prep kernel (cast + 2 transposes + wx pad) ----------------
__global__ __launch_bounds__(256) void prep_all(const float* __restrict__ x,
                                                const float* __restrict__ W_in,
                                                const float* __restrict__ W_out,
                                                const float* __restrict__ Wx,
                                                ushort* __restrict__ xbf,
                                                ushort* __restrict__ winT,
                                                ushort* __restrict__ woutT,
                                                ushort* __restrict__ wxT) {
  __shared__ float tile[32][33];
  int b = blockIdx.x, tid = threadIdx.x;
  if (b < 8192) {                       // cast: 8192*256 float4
    int i = b * 256 + tid;
    float4 v = ((const float4*)x)[i];
    ushort4 o;
    o.x = f2bf(v.x); o.y = f2bf(v.y); o.z = f2bf(v.z); o.w = f2bf(v.w);
    ((ushort4*)xbf)[i] = o;
    return;
  }
  b -= 8192;
  const float* in; ushort* out; int R, C, bx, by;
  if (b < 4096)      { in = W_in;  out = winT;  R = 1024; C = 4096; bx = b & 127; by = b >> 7; }
  else if (b < 6144) { b -= 4096; in = W_out; out = woutT; R = 2048; C = 1024; bx = b & 31; by = b >> 5; }
  else {                                // wx pad: 384 blocks
    int idx = (b - 6144) * 256 + tid;   // 48*2048
    int j = idx >> 11, k = idx & 2047;
    wxT[idx] = (j < 33) ? f2bf(Wx[k * 33 + j]) : (ushort)0;
    return;
  }
  int xx = tid & 31, yy = tid >> 5;     // 32 x 8
  bx *= 32; by *= 32;
#pragma unroll
  for (int j = 0; j < 32; j += 8)
    tile[yy + j][xx] = in[(size_t)(by + yy + j) * C + bx + xx];
  __syncthreads();
#pragma unroll
  for (int j = 0; j < 32; j += 8)
    out[(size_t)(bx + yy + j) * R + by + xx] = f2bf(tile[xx][yy + j]);
}

// ------------- 8-phase GEMM (best measured, R12): (MR*32)x256, BK=64 -------------
// Unchanged from the 285us baseline. Used for GEMM1 only this round.
template<int OUTMODE, int MR>
__global__ __launch_bounds__(512, 2)
void gemm8p(const ushort* __restrict__ A, const ushort* __restrict__ B,
            void* __restrict__ out0, void* __restrict__ out1,
            int N, int K, int LDK, int MX) {
  constexpr int BM = MR * 32;
  constexpr int H = MR / 2;
  constexpr int AHL = BM / 128;
  constexpr int VM = 2 * AHL + 2;
  extern __shared__ __align__(16) char smem[];
  char* const sBr = smem + 2 * BM * 128;

  const int tid = threadIdx.x, lane = tid & 63, wid = tid >> 6;
  const int wm = wid >> 2, wn = wid & 3;
  const int xcd = blockIdx.x & 7, jb = blockIdx.x >> 3;
  const int mtile = xcd * MX + (jb % MX), ntile = jb / MX;
  const int mbase = mtile * BM, nbase = ntile * 256;
  const int NT = K >> 6;

  const int sr = tid >> 3;
  const int scol = ((tid & 7) ^ (sr & 7)) << 3;
  const ushort* pA = A + (size_t)(mbase + sr) * LDK + scol;
  const ushort* pB = B + (size_t)(nbase + sr) * LDK + scol;

  auto stgA = [&](int buf, int h, int tt) {
#pragma unroll
    for (int r = 0; r < AHL; ++r)
      GLD16(smem + buf * (BM * 128) + (h * (BM / 2) + r * 64) * 128 + wid * 1024,
            pA + (size_t)(h * (BM / 2) + r * 64) * LDK + (size_t)tt * 64);
  };
  auto stgB = [&](int buf, int h, int tt) {
#pragma unroll
    for (int r = 0; r < 2; ++r)
      GLD16(sBr + buf * 32768 + (h * 128 + r * 64) * 128 + wid * 1024,
            pB + (size_t)(h * 128 + r * 64) * LDK + (size_t)tt * 64);
  };

  const int frow = lane & 15, hh = lane >> 4;
  const int sw[2] = { ((hh) ^ (frow & 7)) << 4, ((4 + hh) ^ (frow & 7)) << 4 };
  const int arow = (wm * (MR * 16) + frow) * 128;
  const int brow = (wn * 64 + frow) * 128;

  f32x4 acc[MR][4];
#pragma unroll
  for (int m = 0; m < MR; ++m)
#pragma unroll
    for (int n = 0; n < 4; ++n) acc[m][n] = (f32x4){0.f, 0.f, 0.f, 0.f};

  stgA(0, 0, 0); stgA(0, 1, 0); stgB(0, 0, 0); stgB(0, 1, 0);
  if (NT > 1) { stgA(1, 0, 1); stgA(1, 1, 1); stgB(1, 0, 1); }
  waitcnt_vm<VM>();
  BAR();

  for (int t = 0; t < NT; ++t) {
    const int b = t & 1;
    const char* bA = smem + b * (BM * 128);
    const char* bB = sBr + b * 32768;
    bf16x8 alo[H][2], ahi[H][2], b01[2][2], b23[2][2];

    // ---- P1
#pragma unroll
    for (int m = 0; m < H; ++m)
#pragma unroll
      for (int kk = 0; kk < 2; ++kk)
        alo[m][kk] = *(const bf16x8*)(bA + arow + m * 2048 + sw[kk]);
#pragma unroll
    for (int n = 0; n < 2; ++n)
#pragma unroll
      for (int kk = 0; kk < 2; ++kk)
        b01[n][kk] = *(const bf16x8*)(bB + brow + n * 2048 + sw[kk]);
    if (t + 1 < NT) stgB((t + 1) & 1, 1, t + 1);
    BAR(); LGKM0();
    __builtin_amdgcn_s_setprio(1);
#pragma unroll
    for (int kk = 0; kk < 2; ++kk)
#pragma unroll
      for (int m = 0; m < H; ++m)
#pragma unroll
        for (int n = 0; n < 2; ++n)
          acc[m][n] = __builtin_amdgcn_mfma_f32_16x16x32_bf16(alo[m][kk], b01[n][kk], acc[m][n], 0, 0, 0);
    __builtin_amdgcn_s_setprio(0);
    BAR();

    // ---- P2
#pragma unroll
    for (int m = 0; m < H; ++m)
#pragma unroll
      for (int kk = 0; kk < 2; ++kk)
        ahi[m][kk] = *(const bf16x8*)(bA + arow + (H + m) * 2048 + sw[kk]);
    BAR(); LGKM0();
    __builtin_amdgcn_s_setprio(1);
#pragma unroll
    for (int kk = 0; kk < 2; ++kk)
#pragma unroll
      for (int m = 0; m < H; ++m)
#pragma unroll
        for (int n = 0; n < 2; ++n)
          acc[H + m][n] = __builtin_amdgcn_mfma_f32_16x16x32_bf16(ahi[m][kk], b01[n][kk], acc[H + m][n], 0, 0, 0);
    __builtin_amdgcn_s_setprio(0);
    BAR();

    // ---- P3
#pragma unroll
    for (int n = 0; n < 2; ++n)
#pragma unroll
      for (int kk = 0; kk < 2; ++kk)
        b23[n][kk] = *(const bf16x8*)(bB + brow + (2 + n) * 2048 + sw[kk]);
    if (t + 2 < NT) stgA(b, 0, t + 2);
    BAR(); LGKM0();
    __builtin_amdgcn_s_setprio(1);
#pragma unroll
    for (int kk = 0; kk < 2; ++kk)
#pragma unroll
      for (int m = 0; m < H; ++m)
#pragma unroll
        for (int n = 0; n < 2; ++n)
          acc[H + m][2 + n] = __builtin_amdgcn_mfma_f32_16x16x32_bf16(ahi[m][kk], b23[n][kk], acc[H + m][2 + n], 0, 0, 0);
    __builtin_amdgcn_s_setprio(0);
    BAR();

    // ---- P4
    if (t + 2 < NT) { stgA(b, 1, t + 2); stgB(b, 0, t + 2); }
    __builtin_amdgcn_s_setprio(1);
#pragma unroll
    for (int kk = 0; kk < 2; ++kk)
#pragma unroll
      for (int m = 0; m < H; ++m)
#pragma unroll
        for (int n = 0; n < 2; ++n)
          acc[m][2 + n] = __builtin_amdgcn_mfma_f32_16x16x32_bf16(alo[m][kk], b23[n][kk], acc[m][2 + n], 0, 0, 0);
    __builtin_amdgcn_s_setprio(0);
    if (t + 2 < NT) waitcnt_vm<VM>(); else waitcnt_vm<0>();
    BAR();
  }

  // epilogue: C/D layout col=lane&15, row=(lane>>4)*4+reg  [m89/m91]
  const int crow0 = mbase + wm * (MR * 16) + (lane >> 4) * 4;
  const int ccol0 = wn * 64 + (lane & 15);
  if (OUTMODE == 0) {
    float* po = (float*)out0;
#pragma unroll
    for (int m = 0; m < MR; ++m)
#pragma unroll
      for (int n = 0; n < 4; ++n)
#pragma unroll
        for (int j = 0; j < 4; ++j)
          po[(size_t)(crow0 + m * 16 + j) * N + nbase + ccol0 + n * 16] = acc[m][n][j];
  } else {
    ushort* dst = (nbase < 2048) ? (ushort*)out0 : (ushort*)out1;
    const int cbase = (nbase & 2047) + ccol0;
#pragma unroll
    for (int m = 0; m < MR; ++m)
#pragma unroll
      for (int n = 0; n < 4; ++n)
#pragma unroll
        for (int j = 0; j < 4; ++j)
          dst[(size_t)(crow0 + m * 16 + j) * 2048 + cbase + n * 16] = f2bf(acc[m][n][j]);
  }
}

// ------------- NO-FENCE 3-buf GEMM (A/B test, GEMM3): BM=256 BN=128 BK=64 -------------
// 8 waves (4M x 2N), per-wave 64x64, acc[4][4]. LDS ring: A 3x32KB + B 3x16KB = 144KB.
// Per tile: stage(t+2)->slot (t+2)%3 == (t-1)%3 (its readers drained before t-1's
// end barrier: DS completes in-order, so a wave's last lgkm-wait before its last
// MFMA implies all its reads done; barrier-passage seals cross-wave). Then 16
// ds_reads as plain derefs - NO lgkm0/sched_barrier between reads and MFMA: the
// compiler emits fine-grained lgkmcnt(N) so MFMAs overlap the LDS drain (m97
// behavior; the R14 diagnosis is that explicit lgkm0 serialized 2300cy drain vs
// 1030cy MFMA every tile). End of tile: free lgkm0 (own reads long consumed;
// seals the in-order guarantee), counted vmcnt(6) (forces stage(t+1), issued 2
// tiles back), one barrier. Swizzle identical to gemm8p (0 conflicts).
template<int OUTMODE>
__global__ __launch_bounds__(512, 2)
void gemm_nf(const ushort* __restrict__ A, const ushort* __restrict__ B,
             void* __restrict__ out0, void* __restrict__ out1,
             int N, int K, int LDK, int MX) {
  extern __shared__ __align__(16) char smem[];
  char* const sBr = smem + 98304;       // 3 x 32KB A, then 3 x 16KB B

  const int tid = threadIdx.x, lane = tid & 63, wid = tid >> 6;
  const int wm = wid >> 1, wn = wid & 1;    // 4M x 2N
  const int xcd = blockIdx.x & 7, jb = blockIdx.x >> 3;
  const int mtile = xcd * MX + (jb % MX), ntile = jb / MX;
  const int mbase = mtile * 256, nbase = ntile * 128;
  const int NT = K >> 6;

  const int sr = tid >> 3;
  const int scol = ((tid & 7) ^ (sr & 7)) << 3;
  const ushort* pA = A + (size_t)(mbase + sr) * LDK + scol;
  const ushort* pB = B + (size_t)(nbase + sr) * LDK + scol;

  auto stage = [&](int buf, int tt) {
#pragma unroll
    for (int j = 0; j < 4; ++j)
      GLD16(smem + buf * 32768 + j * 8192 + wid * 1024,
            pA + (size_t)(j * 64) * LDK + (size_t)tt * 64);
#pragma unroll
    for (int j = 0; j < 2; ++j)
      GLD16(sBr + buf * 16384 + j * 8192 + wid * 1024,
            pB + (size_t)(j * 64) * LDK + (size_t)tt * 64);
  };

  const int frow = lane & 15, hh = lane >> 4;
  const int sw[2] = { ((hh) ^ (frow & 7)) << 4, ((4 + hh) ^ (frow & 7)) << 4 };
  const int arow = (wm * 64 + frow) * 128;
  const int brow = (wn * 64 + frow) * 128;

  f32x4 acc[4][4];
#pragma unroll
  for (int m = 0; m < 4; ++m)
#pragma unroll
    for (int n = 0; n < 4; ++n) acc[m][n] = (f32x4){0.f, 0.f, 0.f, 0.f};

  // prologue: tiles 0,1 staged; force tile 0 landed (leave tile 1's 6)
  stage(0, 0);
  if (NT > 1) stage(1, 1);
  waitcnt_vm<6>();
  __builtin_amdgcn_s_barrier();

  int b = 0;
  for (int t = 0; t < NT; ++t) {
    if (t + 2 < NT) {
      int b2 = b + 2; if (b2 >= 3) b2 -= 3;   // == (t-1)%3: readers sealed
      stage(b2, t + 2);
    }
    const char* bA = smem + b * 32768;
    const char* bB = sBr + b * 16384;

    bf16x8 af[4][2], bv[4][2];
#pragma unroll
    for (int m = 0; m < 4; ++m)
#pragma unroll
      for (int kk = 0; kk < 2; ++kk)
        af[m][kk] = *(const bf16x8*)(bA + arow + m * 2048 + sw[kk]);
#pragma unroll
    for (int n = 0; n < 4; ++n)
#pragma unroll
      for (int kk = 0; kk < 2; ++kk)
        bv[n][kk] = *(const bf16x8*)(bB + brow + n * 2048 + sw[kk]);

    __builtin_amdgcn_s_setprio(1);
#pragma unroll
    for (int kk = 0; kk < 2; ++kk)
#pragma unroll
      for (int m = 0; m < 4; ++m)
#pragma unroll
        for (int n = 0; n < 4; ++n)
          acc[m][n] = __builtin_amdgcn_mfma_f32_16x16x32_bf16(af[m][kk], bv[n][kk], acc[m][n], 0, 0, 0);
    __builtin_amdgcn_s_setprio(0);

    // end of tile: free own-read drain + counted vmcnt + one barrier
    asm volatile("s_waitcnt lgkmcnt(0)" ::: "memory");
    if (t + 2 < NT) waitcnt_vm<6>(); else waitcnt_vm<0>();
    __builtin_amdgcn_s_barrier();
    b = (b == 2) ? 0 : b + 1;
  }

  // epilogue: C/D layout col=lane&15, row=(lane>>4)*4+reg  [m89/m91]
  const int crow0 = mbase + wm * 64 + (lane >> 4) * 4;
  const int ccol0 = nbase + wn * 64 + (lane & 15);
  if (OUTMODE == 0) {
    float* po = (float*)out0;
#pragma unroll
    for (int m = 0; m < 4; ++m)
#pragma unroll
      for (int n = 0; n < 4; ++n)
#pragma unroll
        for (int j = 0; j < 4; ++j)
          po[(size_t)(crow0 + m * 16 + j) * N + ccol0 + n * 16] = acc[m][n][j];
  } else {
    ushort* dst = (nbase < 2048) ? (ushort*)out0 : (ushort*)out1;
    const int cbase = (nbase & 2047) + wn * 64 + (lane & 15);
#pragma unroll
    for (int m = 0; m < 4; ++m)
#pragma unroll
      for (int n = 0; n < 4; ++n)
#pragma unroll
        for (int j = 0; j < 4; ++j)
          dst[(size_t)(crow0 + m * 16 + j) * 2048 + cbase + n * 16] = f2bf(acc[m][n][j]);
  }
}

// ---------------- thin GEMM: parts[j] = xs @ W_x (N=48 pad), 4-way split-K ----------------
__global__ __launch_bounds__(256) void gemm_thin(const ushort* __restrict__ A,
                                                 const ushort* __restrict__ Bw,
                                                 float* __restrict__ part) {
  __shared__ __align__(16) ushort sA[128 * 64];
  __shared__ __align__(16) ushort sB[48 * 64];
  const int tid = threadIdx.x, lane = tid & 63, wid = tid >> 6;
  const int mbase = blockIdx.x * 128;
  const int kbase = blockIdx.y * 512;
  const int frow = lane & 15, fke = (lane >> 4) * 8;

  f32x4 acc[2][3];
#pragma unroll
  for (int m = 0; m < 2; ++m)
#pragma unroll
    for (int n = 0; n < 3; ++n) acc[m][n] = (f32x4){0.f, 0.f, 0.f, 0.f};

  for (int k0 = 0; k0 < 512; k0 += 64) {
#pragma unroll
    for (int j = 0; j < 4; ++j) {
      int o = tid * 16 + j * 4096;
      int row = o >> 7, ke = ((o >> 4) & 7) * 8;
      GLD16((char*)sA + wid * 1024 + j * 4096,
            A + (size_t)(mbase + row) * DINNER + kbase + k0 + ke);
    }
    for (int i = tid; i < 384; i += 256) {
      int brow = i >> 3, kc = (i & 7) * 8;
      *(bf16x8*)&sB[brow * 64 + kc] = *(const bf16x8*)(Bw + (size_t)brow * DINNER + kbase + k0 + kc);
    }
    __syncthreads();
    bf16x8 af[2][2], bf_[3][2];
#pragma unroll
    for (int m = 0; m < 2; ++m)
#pragma unroll
      for (int ks = 0; ks < 2; ++ks)
        af[m][ks] = *(const bf16x8*)&sA[(wid * 32 + m * 16 + frow) * 64 + ks * 32 + fke];
#pragma unroll
    for (int n = 0; n < 3; ++n)
#pragma unroll
      for (int ks = 0; ks < 2; ++ks)
        bf_[n][ks] = *(const bf16x8*)&sB[(n * 16 + frow) * 64 + ks * 32 + fke];
#pragma unroll
    for (int ks = 0; ks < 2; ++ks)
#pragma unroll
      for (int m = 0; m < 2; ++m)
#pragma unroll
        for (int n = 0; n < 3; ++n)
          acc[m][n] = __builtin_amdgcn_mfma_f32_16x16x32_bf16(af[m][ks], bf_[n][ks], acc[m][n], 0, 0, 0);
    __syncthreads();
  }
  float* po = part + (size_t)blockIdx.y * (T_SEQ * 48);
#pragma unroll
  for (int m = 0; m < 2; ++m)
#pragma unroll
    for (int n = 0; n < 3; ++n)
#pragma unroll
      for (int j = 0; j < 4; ++j) {
        int rr = mbase + wid * 32 + m * 16 + (lane >> 4) * 4 + j;
        int cc = n * 16 + (lane & 15);
        po[(size_t)rr * 48 + cc] = acc[m][n][j];
      }
}

// -------- depthwise causal conv (DC=4) + silu, scalar (coalesced weights) --------
__global__ __launch_bounds__(256) void conv_silu(const ushort* __restrict__ xc,
                                                 const float* __restrict__ cw,
                                                 const float* __restrict__ cb,
                                                 ushort* __restrict__ xs) {
  int idx = blockIdx.x * 256 + threadIdx.x;
  int t = idx >> 11, d = idx & 2047;
  float4 w = *(const float4*)(cw + d * 4);
  float a = cb[d];
  const float wk[4] = {w.x, w.y, w.z, w.w};
#pragma unroll
  for (int k = 0; k < 4; ++k) {
    int tt = t - 3 + k;
    if (tt >= 0) a += bf2f(xc[(size_t)tt * 2048 + d]) * wk[k];
  }
  float s = a / (1.f + expf(-a));
  xs[idx] = f2bf(s);
}

// ---- fused: split-K reduce + delta/abar/bbar/cc + chunk products P ----
__global__ __launch_bounds__(256) void precompute_k(const float* __restrict__ part,
                                                    const float* __restrict__ A_log,
                                                    float* __restrict__ abar,
                                                    float* __restrict__ bbar,
                                                    float* __restrict__ cc,
                                                    float* __restrict__ P) {
  __shared__ float ld[256 * 33];
  const int t0 = blockIdx.x * 256, tid = threadIdx.x;
  for (int i = tid; i < 256 * 33; i += 256) {
    int r = i / 33, col = i - r * 33;
    size_t off = (size_t)(t0 + r) * 48 + col;
    ld[i] = part[off] + part[(size_t)T_SEQ * 48 + off] +
            part[2 * (size_t)T_SEQ * 48 + off] + part[3 * (size_t)T_SEQ * 48 + off];
  }
  __syncthreads();
  const float* r = &ld[tid * 33];
  float v = r[0];
  float delta = (v > 20.f) ? v : log1pf(expf(v));
  int t = t0 + tid;
#pragma unroll
  for (int n = 0; n < NSTATE; ++n) {
    float A = -expf(A_log[n]);
    abar[t * 16 + n] = expf(delta * A);
    bbar[t * 16 + n] = delta * r[1 + n];
    cc[t * 16 + n]   = r[17 + n];
  }
  float s = delta;
#pragma unroll
  for (int off = 32; off > 0; off >>= 1) s += __shfl_down(s, off);
  s = __shfl(s, 0);
  int lane = tid & 63, c = blockIdx.x * 4 + (tid >> 6);
  if (lane < 16) P[c * 16 + lane] = expf(-expf(A_log[lane]) * s);
}

// ---------------- scan pass 1 (hend bf16) ----------------
__global__ __launch_bounds__(256) void scan1(const ushort* __restrict__ xs,
                                             const float* __restrict__ abar,
                                             const float* __restrict__ bbar,
                                             ushort* __restrict__ hend) {
  int c = blockIdx.x;
  int d = blockIdx.y * 256 + threadIdx.x;
  __shared__ float s_ab[CL * 16], s_bb[CL * 16];
  for (int e = threadIdx.x; e < CL * 16; e += 256) {
    s_ab[e] = abar[(size_t)c * CL * 16 + e];
    s_bb[e] = bbar[(size_t)c * CL * 16 + e];
  }
  __syncthreads();
  float h[16];
#pragma unroll
  for (int n = 0; n < 16; ++n) h[n] = 0.f;
  int tbase = c * CL;
  for (int i = 0; i < CL; ++i) {
    float x = bf2f(xs[(size_t)(tbase + i) * DINNER + d]);
#pragma unroll
    for (int n = 0; n < 16; ++n) h[n] = s_ab[i * 16 + n] * h[n] + s_bb[i * 16 + n] * x;
  }
  ushort* o = hend + ((size_t)c * DINNER + d) * 16;
  bf16x8 o0, o1;
#pragma unroll
  for (int q = 0; q < 8; ++q) { o0[q] = (short)f2bf(h[q]); o1[q] = (short)f2bf(h[8 + q]); }
  *(bf16x8*)o = o0;
  *(bf16x8*)(o + 8) = o1;
}

// ---------------- scan pass 2: blocked-prefetch carry scan ----------------
__global__ __launch_bounds__(128) void scan2(const ushort* __restrict__ hend,
                                             const float* __restrict__ P,
                                             ushort* __restrict__ hin) {
  int idx = blockIdx.x * 128 + threadIdx.x;
  int n = idx & 15;
  float h = 0.f;
  for (int g = 0; g < 16; ++g) {
    float e[8], p[8];
#pragma unroll
    for (int j = 0; j < 8; ++j) {
      e[j] = bf2f(hend[(size_t)(g * 8 + j) * 32768 + idx]);
      p[j] = P[(g * 8 + j) * 16 + n];
    }
#pragma unroll
    for (int j = 0; j < 8; ++j) {
      hin[(size_t)(g * 8 + j) * 32768 + idx] = f2bf(h);
      h = p[j] * h + e[j];
    }
  }
}

// ---------------- scan pass 3 (hin bf16) ----------------
__global__ __launch_bounds__(256) void scan3(const ushort* __restrict__ xs,
                                             const ushort* __restrict__ zb,
                                             const float* __restrict__ abar,
                                             const float* __restrict__ bbar,
                                             const float* __restrict__ cc,
                                             const ushort* __restrict__ hin,
                                             const float* __restrict__ Dv,
                                             ushort* __restrict__ y) {
  int c = blockIdx.x;
  int d = blockIdx.y * 256 + threadIdx.x;
  __shared__ float s_ab[CL * 16], s_bb[CL * 16], s_cc[CL * 16];
  for (int e = threadIdx.x; e < CL * 16; e += 256) {
    s_ab[e] = abar[(size_t)c * CL * 16 + e];
    s_bb[e] = bbar[(size_t)c * CL * 16 + e];
    s_cc[e] = cc[(size_t)c * CL * 16 + e];
  }
  __syncthreads();
  float h[16];
  const ushort* hi = hin + ((size_t)c * DINNER + d) * 16;
  bf16x8 h0 = *(const bf16x8*)hi, h1 = *(const bf16x8*)(hi + 8);
#pragma unroll
  for (int q = 0; q < 8; ++q) { h[q] = bf2f((ushort)h0[q]); h[8 + q] = bf2f((ushort)h1[q]); }
  float Dd = Dv[d];
  int tbase = c * CL;
  for (int i = 0; i < CL; ++i) {
    size_t t = tbase + i;
    float x = bf2f(xs[t * DINNER + d]);
    float ys = 0.f;
#pragma unroll
    for (int n = 0; n < 16; ++n) {
      h[n] = s_ab[i * 16 + n] * h[n] + s_bb[i * 16 + n] * x;
      ys += s_cc[i * 16 + n] * h[n];
    }
    float z = bf2f(zb[t * 2048 + d]);
    float yv = (ys + Dd * x) * (z / (1.f + expf(-z)));
    y[t * DINNER + d] = f2bf(yv);
  }
}

// ---------------- launch ----------------
extern "C" void kernel_launch(void* const* d_in, const int* in_sizes, int n_in,
                              void* d_out, int out_size, void* d_ws, size_t ws_size,
                              hipStream_t stream) {
  const float* x      = (const float*)d_in[0];
  const float* W_in   = (const float*)d_in[1];
  const float* conv_w = (const float*)d_in[2];
  const float* conv_b = (const float*)d_in[3];
  const float* W_x    = (const float*)d_in[4];
  const float* A_log  = (const float*)d_in[5];
  const float* Dv     = (const float*)d_in[6];
  const float* W_out  = (const float*)d_in[7];
  float* out = (float*)d_out;

  char* w = (char*)d_ws;
  auto alloc = [&](size_t bytes) { char* p = w; w += (bytes + 255) & ~(size_t)255; return p; };

  ushort* xbf   = (ushort*)alloc((size_t)T_SEQ * DMODEL * 2);
  ushort* winT  = (ushort*)alloc((size_t)4096 * 1024 * 2);
  ushort* woutT = (ushort*)alloc((size_t)1024 * 2048 * 2);
  ushort* wxT   = (ushort*)alloc((size_t)48 * 2048 * 2);
  ushort* xc    = (ushort*)alloc((size_t)T_SEQ * DINNER * 2);
  ushort* zb    = (ushort*)alloc((size_t)T_SEQ * DINNER * 2);
  ushort* xs    = (ushort*)alloc((size_t)T_SEQ * DINNER * 2);
  float*  parts = (float*) alloc((size_t)4 * T_SEQ * 48 * 4);
  float*  abar  = (float*) alloc((size_t)T_SEQ * 16 * 4);
  float*  bbar  = (float*) alloc((size_t)T_SEQ * 16 * 4);
  float*  ccb   = (float*) alloc((size_t)T_SEQ * 16 * 4);
  float*  P     = (float*) alloc((size_t)NCH * 16 * 4);
  ushort* hend  = (ushort*)alloc((size_t)NCH * DINNER * 16 * 2);
  ushort* hin   = (ushort*)alloc((size_t)NCH * DINNER * 16 * 2);
  ushort* ybf   = (ushort*)alloc((size_t)T_SEQ * DINNER * 2);

  auto kg1 = gemm8p<1, 8>;   // 256x256, bf16 split out (best measured)
  auto kg3 = gemm_nf<0>;     // no-fence 3-buf 256x128 (A/B test)
  hipFuncSetAttribute(reinterpret_cast<const void*>(kg1),
                      hipFuncAttributeMaxDynamicSharedMemorySize, 131072);
  hipFuncSetAttribute(reinterpret_cast<const void*>(kg3),
                      hipFuncAttributeMaxDynamicSharedMemorySize, 147456);

  // fused prep: cast + W_in^T + W_out^T + wx pad
  prep_all<<<dim3(14720), 256, 0, stream>>>(x, W_in, W_out, W_x, xbf, winT, woutT, wxT);

  // GEMM1: [xc|z] = x @ W_in (8192x4096, K=1024); 512 blocks, MX=4
  kg1<<<dim3(512), 512, 131072, stream>>>(xbf, winT, xc, zb, 4096, 1024, 1024, 4);

  // conv + silu
  conv_silu<<<(T_SEQ * DINNER) / 256, 256, 0, stream>>>(xc, conv_w, conv_b, xs);

  // GEMM2: parts = xs @ W_x (N=48 pad, split-K 4)
  gemm_thin<<<dim3(T_SEQ / 128, 4), 256, 0, stream>>>(xs, wxT, parts);

  // fused reduce + precompute + chunk products
  precompute_k<<<32, 256, 0, stream>>>(parts, A_log, abar, bbar, ccb, P);

  // 3-pass chunked scan (bf16 carries)
  scan1<<<dim3(NCH, DINNER / 256), 256, 0, stream>>>(xs, abar, bbar, hend);
  scan2<<<256, 128, 0, stream>>>(hend, P, hin);
  scan3<<<dim3(NCH, DINNER / 256), 256, 0, stream>>>(xs, zb, abar, bbar, ccb, hin, Dv, ybf);

  // GEMM3: out = y @ W_out (8192x1024, K=2048); 32m x 8n = 256 blocks, MX=4
  kg3<<<dim3(256), 512, 147456, stream>>>(ybf, woutT, out, nullptr, 1024, 2048, 2048, 4);
}